// Round 2
// baseline (444.141 us; speedup 1.0000x reference)
//
#include <hip/hip_runtime.h>
#include <cmath>

// =====================================================================
// S4-style SSM layer, N=64, L=2^22, computed as an EXACT chunked linear
// recurrence (mathematically identical to the reference's FFT conv):
//   x[t] = Ab x[t-1] + Bb u[t],  y[t] = Cb x[t] + D u[t]
// SISO (B:[N,1], C:[1,N]) => intra-chunk part is a SCALAR causal conv
// with Kloc[i] = Cb Ab^i Bb; only chunk-boundary states need the matrix
// scan. Pipeline:
//   k_setup  : inverse (Gauss-Jordan), Ab/Bb, Pow[s]=Ab^(2^s) s=0..15,
//              Xcol[i]=Ab^i Bb, Rt[n][i]=(Cb Ab^(i+1))[n], Kloc (1 block)
//   k_f      : f[c][n] = sum_j Xcol[MC-1-j][n] u[c*MC+j]
//   k_scan1  : per-segment scan (from 0) -> segment carries
//   k_scantop: exact top-level scan over segments with Q=Ab^(2^15)
//   k_scan2  : re-scan seeded w/ segment init; F[] becomes Xinit[c]
//   k_final  : y = Rt.Xinit + tri-conv(Kloc,u) + D*u
// Scan kernels are single-wave blocks: the x-broadcast uses
// __builtin_amdgcn_readlane (SGPR broadcast, no LDS, no barriers) and
// the F/carry global load is software-pipelined one step ahead.
// =====================================================================

#define NST 64
#define LSEQ 4194304
#define MC 256
#define NCHUNK (LSEQ / MC)   // 16384
#define SEG 128
#define NSEG (NCHUNK / SEG)  // 128
#define NPOW 16              // Pow[s] = Ab^(2^s); P=Pow[8]=Ab^MC, Q=Pow[15]

// ---- workspace layout (float offsets); total 1,163,584 floats (~4.44 MB)
#define POW_OFF 0
#define BB_OFF (NPOW * 4096)                 // 65536
#define XCOL_OFF (BB_OFF + 64)               // 65600   Xcol[i*64+n]
#define KL_OFF (XCOL_OFF + MC * 64)          // 81984   Kloc[i]
#define RT_OFF (KL_OFF + MC)                 // 82240   Rt[n*MC+i]
#define F_OFF (RT_OFF + 64 * MC)             // 98624   F[c*64+n] (later Xinit)
#define CARRY_OFF (F_OFF + NCHUNK * 64)      // 1147200
#define SEGINIT_OFF (CARRY_OFF + NSEG * 64)  // 1155392
#define WS_FLOATS (SEGINIT_OFF + NSEG * 64)  // 1163584

// broadcast lane k of x to all lanes via SGPR (k is compile-time constant
// after unroll; single-wave blocks so no sync needed)
__device__ __forceinline__ float bcast(float x, int k) {
  return __int_as_float(__builtin_amdgcn_readlane(__float_as_int(x), k));
}

// ---------------------------------------------------------------------
// K1: one-block setup. Phases: Gauss-Jordan inverse -> Ab,Bb -> 15
// squarings -> Xcol/Rt log-doubling -> Kloc. Single workgroup so plain
// __syncthreads() orders all global RAW within the kernel.
// ---------------------------------------------------------------------
__global__ __launch_bounds__(1024) void k_setup(
    const float* __restrict__ A, const float* __restrict__ Bv,
    const float* __restrict__ Cv, const float* __restrict__ lstep,
    float* __restrict__ ws) {
  __shared__ __align__(16) float sm[8704];
  const int t = threadIdx.x;
  const float h = 0.5f * expf(lstep[0]);  // step/2

  // ---- P1: Maug = [I - h*A | I] (stride 129), Gauss-Jordan (no pivoting:
  //      matrix is (1+1.5h)I - hW, strongly diagonally dominant)
  for (int idx = t; idx < 64 * 128; idx += 1024) {
    int r = idx >> 7, c = idx & 127;
    float v;
    if (c < 64)
      v = (r == c ? 1.0f : 0.0f) - h * A[r * 64 + c];
    else
      v = (r == (c - 64)) ? 1.0f : 0.0f;
    sm[r * 129 + c] = v;
  }
  __syncthreads();
  for (int k = 0; k < 64; ++k) {
    if (t < 64) sm[8256 + t] = sm[t * 129 + k];  // colk (pre-scale)
    __syncthreads();
    float pinv = 1.0f / sm[8256 + k];
    if (t < 128) sm[k * 129 + t] *= pinv;  // scale pivot row
    __syncthreads();
    for (int idx = t; idx < 64 * 128; idx += 1024) {
      int r = idx >> 7, c = idx & 127;
      if (r != k) sm[r * 129 + c] -= sm[8256 + r] * sm[k * 129 + c];
    }
    __syncthreads();
  }
  // BL(r,c) = sm[r*129 + 64 + c]

  // ---- P2: Ab = BL + h*(BL@A) -> Pow[0];  Bb = step*(BL@B)
  for (int idx = t; idx < 4096; idx += 1024) {
    int r = idx >> 6, c = idx & 63;
    float acc = 0.f;
    for (int k = 0; k < 64; ++k) acc += sm[r * 129 + 64 + k] * A[k * 64 + c];
    ws[POW_OFF + r * 64 + c] = sm[r * 129 + 64 + c] + h * acc;
  }
  if (t < 64) {
    float acc = 0.f;
    for (int k = 0; k < 64; ++k) acc += sm[t * 129 + 64 + k] * Bv[k];
    ws[BB_OFF + t] = 2.0f * h * acc;
  }
  __syncthreads();  // protect sm before squaring buffers reuse it

  // ---- P3: squarings Pow[s] = Pow[s-1]^2, s=1..15. Double-buffer in LDS,
  //      stride 68 floats (16B-aligned rows for float4 b-reads).
  for (int idx = t; idx < 4096; idx += 1024)
    sm[(idx >> 6) * 68 + (idx & 63)] = ws[POW_OFF + idx];
  __syncthreads();
  for (int s = 1; s < NPOW; ++s) {
    float* src = sm + ((s & 1) ? 0 : 4352);
    float* dst = sm + ((s & 1) ? 4352 : 0);
    const int r = t >> 4, c0 = (t & 15) << 2;
    float4 acc = {0.f, 0.f, 0.f, 0.f};
#pragma unroll 8
    for (int k = 0; k < 64; ++k) {
      float a = src[r * 68 + k];
      const float4 b = *(const float4*)&src[k * 68 + c0];
      acc.x += a * b.x; acc.y += a * b.y; acc.z += a * b.z; acc.w += a * b.w;
    }
    *(float4*)&dst[r * 68 + c0] = acc;
    *(float4*)&ws[POW_OFF + s * 4096 + r * 64 + c0] = acc;
    __syncthreads();
  }

  // ---- P4: log-doubling of Xcol (Ab^i Bb) and Rt (Cb Ab^(i+1), transposed)
  if (t < 64) {
    ws[XCOL_OFF + t] = ws[BB_OFF + t];  // Xcol[0] = Bb
  } else if (t < 128) {
    int n = t - 64;  // R[0] = Cb @ Ab
    float acc = 0.f;
    for (int k = 0; k < 64; ++k) acc += Cv[k] * ws[POW_OFF + k * 64 + n];
    ws[RT_OFF + n * MC + 0] = acc;
  }
  for (int s = 0; s < 8; ++s) {
    __syncthreads();  // previous produce done
    for (int idx = t; idx < 4096; idx += 1024)  // M = Pow[s], stride 65
      sm[(idx >> 6) * 65 + (idx & 63)] = ws[POW_OFF + s * 4096 + idx];
    __syncthreads();
    const int cnt = 1 << s;  // produce i in [cnt, 2*cnt)
    for (int idx = t; idx < cnt * 64; idx += 1024) {
      int ir = cnt + (idx >> 6), n = idx & 63, isrc = ir - cnt;
      float xv = 0.f, rv = 0.f;
#pragma unroll 8
      for (int k = 0; k < 64; ++k) {
        xv += sm[n * 65 + k] * ws[XCOL_OFF + isrc * 64 + k];
        rv += sm[k * 65 + n] * ws[RT_OFF + k * MC + isrc];
      }
      ws[XCOL_OFF + ir * 64 + n] = xv;
      ws[RT_OFF + n * MC + ir] = rv;
    }
  }
  __syncthreads();

  // ---- P5: Kloc[i] = Cb . Xcol[i]  (one wave per i, shuffle reduce)
  {
    const int w = t >> 6, lane = t & 63;
    for (int i = w; i < MC; i += 16) {
      float p = Cv[lane] * ws[XCOL_OFF + i * 64 + lane];
#pragma unroll
      for (int m = 32; m >= 1; m >>= 1) p += __shfl_xor(p, m, 64);
      if (lane == 0) ws[KL_OFF + i] = p;
    }
  }
}

// ---------------------------------------------------------------------
// K2: F[c][n] = sum_j Xcol[MC-1-j][n] * u[c*MC+j]. 16 chunks per block.
// ---------------------------------------------------------------------
__global__ __launch_bounds__(256) void k_f(const float* __restrict__ u,
                                           float* __restrict__ ws) {
  __shared__ __align__(16) float us[16 * MC];
  const int t = threadIdx.x;
  const int c0 = blockIdx.x * 16;
  for (int idx = t; idx < 16 * MC; idx += 256)
    us[idx] = u[(size_t)c0 * MC + idx];
  __syncthreads();
  const int n = t & 63, g = t >> 6;  // wave g owns chunks c0+4g .. c0+4g+3
  const float* xc = ws + XCOL_OFF;
  const float* ug = us + g * 4 * MC;
  float a0 = 0.f, a1 = 0.f, a2 = 0.f, a3 = 0.f;
  for (int j = 0; j < MC; j += 4) {
    float x0 = xc[(MC - 1 - j) * 64 + n];
    float x1 = xc[(MC - 2 - j) * 64 + n];
    float x2 = xc[(MC - 3 - j) * 64 + n];
    float x3 = xc[(MC - 4 - j) * 64 + n];
    {
      const float4 uv = *(const float4*)&ug[0 * MC + j];
      a0 += x0 * uv.x + x1 * uv.y + x2 * uv.z + x3 * uv.w;
    }
    {
      const float4 uv = *(const float4*)&ug[1 * MC + j];
      a1 += x0 * uv.x + x1 * uv.y + x2 * uv.z + x3 * uv.w;
    }
    {
      const float4 uv = *(const float4*)&ug[2 * MC + j];
      a2 += x0 * uv.x + x1 * uv.y + x2 * uv.z + x3 * uv.w;
    }
    {
      const float4 uv = *(const float4*)&ug[3 * MC + j];
      a3 += x0 * uv.x + x1 * uv.y + x2 * uv.z + x3 * uv.w;
    }
  }
  float* Fb = ws + F_OFF + (size_t)(c0 + g * 4) * 64;
  Fb[0 * 64 + n] = a0;
  Fb[1 * 64 + n] = a1;
  Fb[2 * 64 + n] = a2;
  Fb[3 * 64 + n] = a3;
}

// ---------------------------------------------------------------------
// Scan kernels: ONE wave per block. P-row in registers (lane n = row n);
// x broadcast via readlane (no LDS, no barriers in the serial loop);
// F/carry global load pipelined one step ahead.
// ---------------------------------------------------------------------
#define MATVEC_STEP(preg, xv, a0, a1, a2, a3)          \
  _Pragma("unroll") for (int k = 0; k < 64; k += 4) {  \
    a0 = fmaf(preg[k + 0], bcast(xv, k + 0), a0);      \
    a1 = fmaf(preg[k + 1], bcast(xv, k + 1), a1);      \
    a2 = fmaf(preg[k + 2], bcast(xv, k + 2), a2);      \
    a3 = fmaf(preg[k + 3], bcast(xv, k + 3), a3);      \
  }

__global__ __launch_bounds__(64) void k_scan1(float* __restrict__ ws) {
  __shared__ float Pl[64 * 65];
  const int n = threadIdx.x;
  for (int idx = n; idx < 4096; idx += 64)
    Pl[(idx >> 6) * 65 + (idx & 63)] = ws[POW_OFF + 8 * 4096 + idx];
  __syncthreads();
  float p[64];
#pragma unroll
  for (int k = 0; k < 64; ++k) p[k] = Pl[n * 65 + k];
  float x = 0.f;
  const float* Fp = ws + F_OFF + (size_t)blockIdx.x * SEG * 64;
  float fv = Fp[n];
  for (int c = 0; c < SEG; ++c) {
    float fnext = Fp[(c < SEG - 1 ? c + 1 : c) * 64 + n];  // prefetch
    float a0 = 0.f, a1 = 0.f, a2 = 0.f, a3 = 0.f;
    MATVEC_STEP(p, x, a0, a1, a2, a3)
    x = ((a0 + a1) + (a2 + a3)) + fv;
    fv = fnext;
  }
  ws[CARRY_OFF + blockIdx.x * 64 + n] = x;
}

__global__ __launch_bounds__(64) void k_scantop(float* __restrict__ ws) {
  __shared__ float Ql[64 * 65];
  const int n = threadIdx.x;
  for (int idx = n; idx < 4096; idx += 64)
    Ql[(idx >> 6) * 65 + (idx & 63)] = ws[POW_OFF + 15 * 4096 + idx];
  __syncthreads();
  float q[64];
#pragma unroll
  for (int k = 0; k < 64; ++k) q[k] = Ql[n * 65 + k];
  float x = 0.f;
  float cv = ws[CARRY_OFF + n];
  for (int s = 0; s < NSEG; ++s) {
    float cnext = ws[CARRY_OFF + (s < NSEG - 1 ? s + 1 : s) * 64 + n];
    ws[SEGINIT_OFF + s * 64 + n] = x;  // exclusive: state before segment s
    float a0 = 0.f, a1 = 0.f, a2 = 0.f, a3 = 0.f;
    MATVEC_STEP(q, x, a0, a1, a2, a3)
    x = ((a0 + a1) + (a2 + a3)) + cv;
    cv = cnext;
  }
}

__global__ __launch_bounds__(64) void k_scan2(float* __restrict__ ws) {
  __shared__ float Pl[64 * 65];
  const int n = threadIdx.x;
  for (int idx = n; idx < 4096; idx += 64)
    Pl[(idx >> 6) * 65 + (idx & 63)] = ws[POW_OFF + 8 * 4096 + idx];
  __syncthreads();
  float p[64];
#pragma unroll
  for (int k = 0; k < 64; ++k) p[k] = Pl[n * 65 + k];
  float x = ws[SEGINIT_OFF + blockIdx.x * 64 + n];
  float* Fp = ws + F_OFF + (size_t)blockIdx.x * SEG * 64;
  float fv = Fp[n];
  for (int c = 0; c < SEG; ++c) {
    float fnext = Fp[(c < SEG - 1 ? c + 1 : c) * 64 + n];  // prefetch
    Fp[c * 64 + n] = x;  // overwrite F with Xinit[c] (state BEFORE chunk c)
    float a0 = 0.f, a1 = 0.f, a2 = 0.f, a3 = 0.f;
    MATVEC_STEP(p, x, a0, a1, a2, a3)
    x = ((a0 + a1) + (a2 + a3)) + fv;
    fv = fnext;
  }
}

// ---------------------------------------------------------------------
// K6: y[c*MC+i] = Rt[:,i].Xinit[c] + sum_{j<=i} Kloc[i-j] u[c*MC+j] + D u.
// 8 chunks per block; thread = in-chunk position i.
// ---------------------------------------------------------------------
__global__ __launch_bounds__(256) void k_final(const float* __restrict__ u,
                                               const float* __restrict__ Dv,
                                               const float* __restrict__ ws,
                                               float* __restrict__ out) {
  __shared__ __align__(16) float us[8 * MC];
  __shared__ __align__(16) float kl[MC];
  __shared__ __align__(16) float xin[8 * 64];
  const int t = threadIdx.x;
  const int c0 = blockIdx.x * 8;
  for (int idx = t; idx < 8 * MC; idx += 256)
    us[idx] = u[(size_t)c0 * MC + idx];
  kl[t] = ws[KL_OFF + t];
  for (int idx = t; idx < 8 * 64; idx += 256)
    xin[idx] = ws[F_OFF + (size_t)c0 * 64 + idx];
  __syncthreads();

  float acc[8];
#pragma unroll
  for (int cc = 0; cc < 8; ++cc) acc[cc] = 0.f;

  // boundary term: acc[cc] = sum_n Rt[n][i] * xin[cc][n]  (Rt coalesced in i)
  const float* rt = ws + RT_OFF;
#pragma unroll 4
  for (int nn = 0; nn < 64; nn += 4) {
    float r0 = rt[(nn + 0) * MC + t];
    float r1 = rt[(nn + 1) * MC + t];
    float r2 = rt[(nn + 2) * MC + t];
    float r3 = rt[(nn + 3) * MC + t];
#pragma unroll
    for (int cc = 0; cc < 8; ++cc) {
      const float4 xv = *(const float4*)&xin[cc * 64 + nn];
      acc[cc] += r0 * xv.x + r1 * xv.y + r2 * xv.z + r3 * xv.w;
    }
  }

  // triangular conv: j-quads with float4 u reads; kl reversed -> scalar reads
  const int i = t;
  int j = 0;
  for (; j + 3 <= i; j += 4) {
    float k0 = kl[i - j], k1 = kl[i - j - 1], k2 = kl[i - j - 2],
          k3 = kl[i - j - 3];
#pragma unroll
    for (int cc = 0; cc < 8; ++cc) {
      const float4 uv = *(const float4*)&us[cc * MC + j];
      acc[cc] += k0 * uv.x + k1 * uv.y + k2 * uv.z + k3 * uv.w;
    }
  }
  for (; j <= i; ++j) {
    float kv = kl[i - j];
#pragma unroll
    for (int cc = 0; cc < 8; ++cc) acc[cc] += kv * us[cc * MC + j];
  }

  const float D0 = Dv[0];
#pragma unroll
  for (int cc = 0; cc < 8; ++cc)
    out[(size_t)(c0 + cc) * MC + i] = acc[cc] + D0 * us[cc * MC + i];
}

// ---------------------------------------------------------------------
extern "C" void kernel_launch(void* const* d_in, const int* in_sizes, int n_in,
                              void* d_out, int out_size, void* d_ws,
                              size_t ws_size, hipStream_t stream) {
  (void)in_sizes; (void)n_in; (void)out_size; (void)ws_size;
  const float* u = (const float*)d_in[0];
  const float* A = (const float*)d_in[1];
  const float* B = (const float*)d_in[2];
  const float* C = (const float*)d_in[3];
  const float* D = (const float*)d_in[4];
  const float* ls = (const float*)d_in[5];
  float* ws = (float*)d_ws;  // needs WS_FLOATS*4 ~ 4.44 MB
  float* out = (float*)d_out;

  hipLaunchKernelGGL(k_setup, dim3(1), dim3(1024), 0, stream, A, B, C, ls, ws);
  hipLaunchKernelGGL(k_f, dim3(NCHUNK / 16), dim3(256), 0, stream, u, ws);
  hipLaunchKernelGGL(k_scan1, dim3(NSEG), dim3(64), 0, stream, ws);
  hipLaunchKernelGGL(k_scantop, dim3(1), dim3(64), 0, stream, ws);
  hipLaunchKernelGGL(k_scan2, dim3(NSEG), dim3(64), 0, stream, ws);
  hipLaunchKernelGGL(k_final, dim3(NCHUNK / 8), dim3(256), 0, stream, u, D, ws,
                     out);
}

// Round 3
// 428.171 us; speedup vs baseline: 1.0373x; 1.0373x over previous
//
#include <hip/hip_runtime.h>
#include <cmath>

// =====================================================================
// S4-style SSM layer, N=64, L=2^22, as an EXACT chunked linear recurrence.
//   x[t] = Ab x[t-1] + Bb u[t],  y[t] = Cb x[t] + D u[t]
// Pipeline:
//   k_setup  : GJ solve [I-hA | I+hA | 2hB] -> Ab,Bb; 15 in-place dual
//              squarings (reg-staged) -> Ab^2..Ab^32768; Xcol/Rt via
//              register-matrix matvec chains; Kloc. (1 block)
//   k_f      : f[c][n] = sum_j Xcol[MC-1-j][n] u[c*MC+j]
//   k_scan1  : per-segment scan -> segment carries
//   k_scantop: top-level scan over segments with Ab^(2^15)
//   k_scan2  : re-scan seeded; F[] becomes Xinit[c]
//   k_final  : y = Rt.Xinit + tri-conv(Kloc,u) + D*u
// =====================================================================

#define NST 64
#define LSEQ 4194304
#define MC 256
#define NCHUNK (LSEQ / MC)   // 16384
#define SEG 128
#define NSEG (NCHUNK / SEG)  // 128

// ---- workspace layout (float offsets), ~4.35 MB
#define ABR_OFF 0                  // Ab rows           [64][64]
#define ABT_OFF 4096               // Ab^T rows         [64][64]
#define P4R_OFF 8192               // Ab^16 rows
#define P4T_OFF 12288              // (Ab^16)^T rows
#define P8_OFF 16384               // Ab^256 rows (scan1/2)
#define P15_OFF 20480              // Ab^32768 rows (scantop)
#define BB_OFF 24576               // Bb [64]
#define KL_OFF 24640               // Kloc [256]
#define XCOL_OFF 24896             // Xcol[i*64+n], i<256
#define RTT_OFF 41280              // scratch Rtt[i*64+n]
#define RT_OFF 57664               // Rt[n*MC+i]
#define F_OFF 74048                // F[c*64+n] (later Xinit)
#define CARRY_OFF (F_OFF + NCHUNK * 64)      // 1122624
#define SEGINIT_OFF (CARRY_OFF + NSEG * 64)  // 1130816
#define WS_FLOATS (SEGINIT_OFF + NSEG * 64)  // 1139008

__device__ __forceinline__ float bcast(float x, int k) {
  return __int_as_float(__builtin_amdgcn_readlane(__float_as_int(x), k));
}

// x' = M x, lane n = component n, M rows in registers (m[kq] = row[4kq..4kq+3])
__device__ __forceinline__ float matvec64(const float4 (&m)[16], float x) {
  float a0 = 0.f, a1 = 0.f, a2 = 0.f, a3 = 0.f;
#pragma unroll
  for (int kq = 0; kq < 16; ++kq) {
    a0 = fmaf(m[kq].x, bcast(x, 4 * kq + 0), a0);
    a1 = fmaf(m[kq].y, bcast(x, 4 * kq + 1), a1);
    a2 = fmaf(m[kq].z, bcast(x, 4 * kq + 2), a2);
    a3 = fmaf(m[kq].w, bcast(x, 4 * kq + 3), a3);
  }
  return ((a0 + a1) + (a2 + a3));
}

__device__ __forceinline__ void load_rows(float4 (&m)[16], const float* src,
                                          int lane) {
#pragma unroll
  for (int kq = 0; kq < 16; ++kq)
    m[kq] = *(const float4*)(src + (size_t)lane * 64 + kq * 4);
}

#define CGET(v, cj) ((cj) == 0 ? (v).x : (cj) == 1 ? (v).y : (cj) == 2 ? (v).z : (v).w)

// ---------------------------------------------------------------------
// K1: one-block setup.
// LDS map (floats): GJ G[64][144] = [0,9216) ;
//   after GJ: AR [0,4096), AT [4096,8192), trans [8192,12352)
//   colbuf [12352,12416), xseed [12416,13504), rseed [13504,14592)
// ---------------------------------------------------------------------
__global__ __launch_bounds__(1024) void k_setup(
    const float* __restrict__ A, const float* __restrict__ Bv,
    const float* __restrict__ Cv, const float* __restrict__ lstep,
    float* __restrict__ ws) {
  __shared__ __align__(16) float sm[14592];
  float* colbuf = sm + 12352;
  float* xs = sm + 12416;  // stride 68
  float* rs = sm + 13504;  // stride 68
  const int t = threadIdx.x;
  const int w = t >> 6, lane = t & 63;
  const float h = 0.5f * expf(lstep[0]);

  // ---- P1: Gauss-Jordan on G = [I-hA | I+hA | 2hB | pad], stride 144.
  {
    const int r = t >> 4;
    for (int c = t & 15; c < 144; c += 16) {
      float v = 0.f;
      if (c < 64)
        v = (r == c ? 1.0f : 0.0f) - h * A[r * 64 + c];
      else if (c < 128)
        v = (r == (c - 64) ? 1.0f : 0.0f) + h * A[r * 64 + (c - 64)];
      else if (c == 128)
        v = 2.0f * h * Bv[r];
      sm[r * 144 + c] = v;
    }
  }
  __syncthreads();
  {
    float4* G4 = (float4*)sm;  // row stride 36 quads
    for (int k = 0; k < 64; ++k) {
      if (t < 64) colbuf[t] = sm[t * 144 + k];
      __syncthreads();
      const float pinv = 1.0f / colbuf[k];
      const int r = lane;
      const float mr = colbuf[r] * pinv;
      for (int q = (k >> 2) + w; q <= 32; q += 16) {
        float4 pr = G4[k * 36 + q];
        float4 g = G4[r * 36 + q];
        if (r == k) {
          g.x = pr.x * pinv; g.y = pr.y * pinv;
          g.z = pr.z * pinv; g.w = pr.w * pinv;
        } else {
          g.x = fmaf(-mr, pr.x, g.x); g.y = fmaf(-mr, pr.y, g.y);
          g.z = fmaf(-mr, pr.z, g.z); g.w = fmaf(-mr, pr.w, g.w);
        }
        G4[r * 36 + q] = g;
      }
      __syncthreads();
    }
  }
  // export Ab (cols 64..127) and Bb (col 128) to ws
  for (int idx = t; idx < 4096; idx += 1024) {
    int r = idx >> 6, c = idx & 63;
    ws[ABR_OFF + idx] = sm[r * 144 + 64 + c];
  }
  if (t < 64) ws[BB_OFF + t] = sm[t * 144 + 128];
  __syncthreads();  // G dead; AR/trans regions may be written now

  // ---- build AR (rows) + AT (cols-as-rows) in LDS; export ABT
  {
    float* AR = sm;          // [64][64]
    float* AT = sm + 4096;   // [64][64]
    float* tr = sm + 8192;   // [64][65]
    for (int idx = t; idx < 4096; idx += 1024) {
      float v = ws[ABR_OFF + idx];
      AR[idx] = v;
      tr[(idx & 63) * 65 + (idx >> 6)] = v;  // tr[c][r]
    }
    __syncthreads();
    for (int idx = t; idx < 4096; idx += 1024) {
      float v = tr[(idx >> 6) * 65 + (idx & 63)];
      AT[idx] = v;
      ws[ABT_OFF + idx] = v;
    }
  }
  __syncthreads();

  // ---- P3: 15 in-place dual squarings, 2 waves, 8x4 register tiles
  {
    float4* AR4 = (float4*)sm;           // [64][16] quads
    float4* AT4 = (float4*)(sm + 4096);  // [64][16] quads
    const bool active = t < 128;
    const int r0 = (t >> 4) << 3;   // 0..56 step 8 (for t<128)
    const int c0q = t & 15;         // col quad
    for (int s = 1; s <= 15; ++s) {
      float4 acc[8];
#pragma unroll
      for (int j = 0; j < 8; ++j) acc[j] = {0.f, 0.f, 0.f, 0.f};
      if (active) {
#pragma unroll 8
        for (int k = 0; k < 64; ++k) {
          const float4 b = AR4[k * 16 + c0q];
          const float4 a0 = AT4[k * 16 + (r0 >> 2)];
          const float4 a1 = AT4[k * 16 + (r0 >> 2) + 1];
          acc[0].x = fmaf(a0.x, b.x, acc[0].x); acc[0].y = fmaf(a0.x, b.y, acc[0].y);
          acc[0].z = fmaf(a0.x, b.z, acc[0].z); acc[0].w = fmaf(a0.x, b.w, acc[0].w);
          acc[1].x = fmaf(a0.y, b.x, acc[1].x); acc[1].y = fmaf(a0.y, b.y, acc[1].y);
          acc[1].z = fmaf(a0.y, b.z, acc[1].z); acc[1].w = fmaf(a0.y, b.w, acc[1].w);
          acc[2].x = fmaf(a0.z, b.x, acc[2].x); acc[2].y = fmaf(a0.z, b.y, acc[2].y);
          acc[2].z = fmaf(a0.z, b.z, acc[2].z); acc[2].w = fmaf(a0.z, b.w, acc[2].w);
          acc[3].x = fmaf(a0.w, b.x, acc[3].x); acc[3].y = fmaf(a0.w, b.y, acc[3].y);
          acc[3].z = fmaf(a0.w, b.z, acc[3].z); acc[3].w = fmaf(a0.w, b.w, acc[3].w);
          acc[4].x = fmaf(a1.x, b.x, acc[4].x); acc[4].y = fmaf(a1.x, b.y, acc[4].y);
          acc[4].z = fmaf(a1.x, b.z, acc[4].z); acc[4].w = fmaf(a1.x, b.w, acc[4].w);
          acc[5].x = fmaf(a1.y, b.x, acc[5].x); acc[5].y = fmaf(a1.y, b.y, acc[5].y);
          acc[5].z = fmaf(a1.y, b.z, acc[5].z); acc[5].w = fmaf(a1.y, b.w, acc[5].w);
          acc[6].x = fmaf(a1.z, b.x, acc[6].x); acc[6].y = fmaf(a1.z, b.y, acc[6].y);
          acc[6].z = fmaf(a1.z, b.z, acc[6].z); acc[6].w = fmaf(a1.z, b.w, acc[6].w);
          acc[7].x = fmaf(a1.w, b.x, acc[7].x); acc[7].y = fmaf(a1.w, b.y, acc[7].y);
          acc[7].z = fmaf(a1.w, b.z, acc[7].z); acc[7].w = fmaf(a1.w, b.w, acc[7].w);
        }
      }
      __syncthreads();  // all reads of AR/AT done
      if (active) {
#pragma unroll
        for (int j = 0; j < 8; ++j) AR4[(r0 + j) * 16 + c0q] = acc[j];
#pragma unroll
        for (int cj = 0; cj < 4; ++cj) {
          float4 lo = {CGET(acc[0], cj), CGET(acc[1], cj), CGET(acc[2], cj),
                       CGET(acc[3], cj)};
          float4 hi = {CGET(acc[4], cj), CGET(acc[5], cj), CGET(acc[6], cj),
                       CGET(acc[7], cj)};
          AT4[(c0q * 4 + cj) * 16 + (r0 >> 2)] = lo;
          AT4[(c0q * 4 + cj) * 16 + (r0 >> 2) + 1] = hi;
          if (s == 4) {
            *(float4*)&ws[P4T_OFF + (c0q * 4 + cj) * 64 + r0] = lo;
            *(float4*)&ws[P4T_OFF + (c0q * 4 + cj) * 64 + r0 + 4] = hi;
          }
        }
        if (s == 4 || s == 8 || s == 15) {
          const int off = (s == 4) ? P4R_OFF : (s == 8) ? P8_OFF : P15_OFF;
#pragma unroll
          for (int j = 0; j < 8; ++j)
            *(float4*)&ws[off + (r0 + j) * 64 + c0q * 4] = acc[j];
        }
      }
      __syncthreads();
    }
  }

  // ---- P4a: seed chains. wave0: X (Ab^16), wave8: R ((Ab^T)^16)
  if (w == 0 || w == 8) {
    float4 m[16];
    float x;
    float* sb = (w == 0) ? xs : rs;
    if (w == 0) {
      load_rows(m, ws + P4R_OFF, lane);
      x = ws[BB_OFF + lane];
    } else {
      load_rows(m, ws + ABT_OFF, lane);
      x = matvec64(m, Cv[lane]);  // r0 = Ab^T c  (= Cb Ab, transposed comp)
      load_rows(m, ws + P4T_OFF, lane);
    }
    sb[0 * 68 + lane] = x;
#pragma unroll 1
    for (int g = 1; g < 16; ++g) {
      x = matvec64(m, x);
      sb[g * 68 + lane] = x;
    }
  }
  __syncthreads();

  // ---- P4b: X extension, all 16 waves: Xcol[16w+j]
  {
    float4 m[16];
    load_rows(m, ws + ABR_OFF, lane);
    float x = xs[w * 68 + lane];
#pragma unroll 1
    for (int j = 0; j < 16; ++j) {
      ws[XCOL_OFF + (size_t)(16 * w + j) * 64 + lane] = x;
      if (j < 15) x = matvec64(m, x);
    }
  }
  // ---- P4c: R extension, all 16 waves: Rtt[16w+j]
  {
    float4 m[16];
    load_rows(m, ws + ABT_OFF, lane);
    float r = rs[w * 68 + lane];
#pragma unroll 1
    for (int j = 0; j < 16; ++j) {
      ws[RTT_OFF + (size_t)(16 * w + j) * 64 + lane] = r;
      if (j < 15) r = matvec64(m, r);
    }
  }
  __syncthreads();

  // ---- P4d: transpose Rtt[i][n] -> Rt[n][MC] via LDS staging
  {
    float* tr = sm + 8192;  // [64][65]
    for (int blk = 0; blk < 4; ++blk) {
      for (int idx = t; idx < 4096; idx += 1024) {
        int il = idx >> 6, n = idx & 63;
        tr[n * 65 + il] = ws[RTT_OFF + (size_t)(blk * 64 + il) * 64 + n];
      }
      __syncthreads();
      for (int idx = t; idx < 4096; idx += 1024) {
        int n = idx >> 6, il = idx & 63;
        ws[RT_OFF + (size_t)n * MC + blk * 64 + il] = tr[n * 65 + il];
      }
      __syncthreads();
    }
  }

  // ---- P5: Kloc[i] = Cb . Xcol[i]
  {
    const float cv = Cv[lane];
    for (int i = w; i < MC; i += 16) {
      float p = cv * ws[XCOL_OFF + (size_t)i * 64 + lane];
#pragma unroll
      for (int m = 32; m >= 1; m >>= 1) p += __shfl_xor(p, m, 64);
      if (lane == 0) ws[KL_OFF + i] = p;
    }
  }
}

// ---------------------------------------------------------------------
// K2: F[c][n] = sum_j Xcol[MC-1-j][n] * u[c*MC+j]. 16 chunks per block.
// ---------------------------------------------------------------------
__global__ __launch_bounds__(256) void k_f(const float* __restrict__ u,
                                           float* __restrict__ ws) {
  __shared__ __align__(16) float us[16 * MC];
  const int t = threadIdx.x;
  const int c0 = blockIdx.x * 16;
  for (int idx = t; idx < 16 * MC; idx += 256)
    us[idx] = u[(size_t)c0 * MC + idx];
  __syncthreads();
  const int n = t & 63, g = t >> 6;
  const float* xc = ws + XCOL_OFF;
  const float* ug = us + g * 4 * MC;
  float a0 = 0.f, a1 = 0.f, a2 = 0.f, a3 = 0.f;
  for (int j = 0; j < MC; j += 4) {
    float x0 = xc[(MC - 1 - j) * 64 + n];
    float x1 = xc[(MC - 2 - j) * 64 + n];
    float x2 = xc[(MC - 3 - j) * 64 + n];
    float x3 = xc[(MC - 4 - j) * 64 + n];
    {
      const float4 uv = *(const float4*)&ug[0 * MC + j];
      a0 += x0 * uv.x + x1 * uv.y + x2 * uv.z + x3 * uv.w;
    }
    {
      const float4 uv = *(const float4*)&ug[1 * MC + j];
      a1 += x0 * uv.x + x1 * uv.y + x2 * uv.z + x3 * uv.w;
    }
    {
      const float4 uv = *(const float4*)&ug[2 * MC + j];
      a2 += x0 * uv.x + x1 * uv.y + x2 * uv.z + x3 * uv.w;
    }
    {
      const float4 uv = *(const float4*)&ug[3 * MC + j];
      a3 += x0 * uv.x + x1 * uv.y + x2 * uv.z + x3 * uv.w;
    }
  }
  float* Fb = ws + F_OFF + (size_t)(c0 + g * 4) * 64;
  Fb[0 * 64 + n] = a0;
  Fb[1 * 64 + n] = a1;
  Fb[2 * 64 + n] = a2;
  Fb[3 * 64 + n] = a3;
}

// ---------------------------------------------------------------------
// Scan kernels: ONE wave per block, P rows in registers, readlane bcast.
// ---------------------------------------------------------------------
#define MATVEC_STEP(preg, xv, a0, a1, a2, a3)          \
  _Pragma("unroll") for (int k = 0; k < 64; k += 4) {  \
    a0 = fmaf(preg[k + 0], bcast(xv, k + 0), a0);      \
    a1 = fmaf(preg[k + 1], bcast(xv, k + 1), a1);      \
    a2 = fmaf(preg[k + 2], bcast(xv, k + 2), a2);      \
    a3 = fmaf(preg[k + 3], bcast(xv, k + 3), a3);      \
  }

__global__ __launch_bounds__(64) void k_scan1(float* __restrict__ ws) {
  __shared__ float Pl[64 * 65];
  const int n = threadIdx.x;
  for (int idx = n; idx < 4096; idx += 64)
    Pl[(idx >> 6) * 65 + (idx & 63)] = ws[P8_OFF + idx];
  __syncthreads();
  float p[64];
#pragma unroll
  for (int k = 0; k < 64; ++k) p[k] = Pl[n * 65 + k];
  float x = 0.f;
  const float* Fp = ws + F_OFF + (size_t)blockIdx.x * SEG * 64;
  float fv = Fp[n];
  for (int c = 0; c < SEG; ++c) {
    float fnext = Fp[(c < SEG - 1 ? c + 1 : c) * 64 + n];
    float a0 = 0.f, a1 = 0.f, a2 = 0.f, a3 = 0.f;
    MATVEC_STEP(p, x, a0, a1, a2, a3)
    x = ((a0 + a1) + (a2 + a3)) + fv;
    fv = fnext;
  }
  ws[CARRY_OFF + blockIdx.x * 64 + n] = x;
}

__global__ __launch_bounds__(64) void k_scantop(float* __restrict__ ws) {
  __shared__ float Ql[64 * 65];
  const int n = threadIdx.x;
  for (int idx = n; idx < 4096; idx += 64)
    Ql[(idx >> 6) * 65 + (idx & 63)] = ws[P15_OFF + idx];
  __syncthreads();
  float q[64];
#pragma unroll
  for (int k = 0; k < 64; ++k) q[k] = Ql[n * 65 + k];
  float x = 0.f;
  float cv = ws[CARRY_OFF + n];
  for (int s = 0; s < NSEG; ++s) {
    float cnext = ws[CARRY_OFF + (s < NSEG - 1 ? s + 1 : s) * 64 + n];
    ws[SEGINIT_OFF + s * 64 + n] = x;
    float a0 = 0.f, a1 = 0.f, a2 = 0.f, a3 = 0.f;
    MATVEC_STEP(q, x, a0, a1, a2, a3)
    x = ((a0 + a1) + (a2 + a3)) + cv;
    cv = cnext;
  }
}

__global__ __launch_bounds__(64) void k_scan2(float* __restrict__ ws) {
  __shared__ float Pl[64 * 65];
  const int n = threadIdx.x;
  for (int idx = n; idx < 4096; idx += 64)
    Pl[(idx >> 6) * 65 + (idx & 63)] = ws[P8_OFF + idx];
  __syncthreads();
  float p[64];
#pragma unroll
  for (int k = 0; k < 64; ++k) p[k] = Pl[n * 65 + k];
  float x = ws[SEGINIT_OFF + blockIdx.x * 64 + n];
  float* Fp = ws + F_OFF + (size_t)blockIdx.x * SEG * 64;
  float fv = Fp[n];
  for (int c = 0; c < SEG; ++c) {
    float fnext = Fp[(c < SEG - 1 ? c + 1 : c) * 64 + n];
    Fp[c * 64 + n] = x;  // overwrite F with Xinit[c]
    float a0 = 0.f, a1 = 0.f, a2 = 0.f, a3 = 0.f;
    MATVEC_STEP(p, x, a0, a1, a2, a3)
    x = ((a0 + a1) + (a2 + a3)) + fv;
    fv = fnext;
  }
}

// ---------------------------------------------------------------------
// K6: y[c*MC+i] = Rt[:,i].Xinit[c] + tri-conv + D*u. 8 chunks/block.
// ---------------------------------------------------------------------
__global__ __launch_bounds__(256) void k_final(const float* __restrict__ u,
                                               const float* __restrict__ Dv,
                                               const float* __restrict__ ws,
                                               float* __restrict__ out) {
  __shared__ __align__(16) float us[8 * MC];
  __shared__ __align__(16) float kl[MC];
  __shared__ __align__(16) float xin[8 * 64];
  const int t = threadIdx.x;
  const int c0 = blockIdx.x * 8;
  for (int idx = t; idx < 8 * MC; idx += 256)
    us[idx] = u[(size_t)c0 * MC + idx];
  kl[t] = ws[KL_OFF + t];
  for (int idx = t; idx < 8 * 64; idx += 256)
    xin[idx] = ws[F_OFF + (size_t)c0 * 64 + idx];
  __syncthreads();

  float acc[8];
#pragma unroll
  for (int cc = 0; cc < 8; ++cc) acc[cc] = 0.f;

  const float* rt = ws + RT_OFF;
#pragma unroll 4
  for (int nn = 0; nn < 64; nn += 4) {
    float r0 = rt[(nn + 0) * MC + t];
    float r1 = rt[(nn + 1) * MC + t];
    float r2 = rt[(nn + 2) * MC + t];
    float r3 = rt[(nn + 3) * MC + t];
#pragma unroll
    for (int cc = 0; cc < 8; ++cc) {
      const float4 xv = *(const float4*)&xin[cc * 64 + nn];
      acc[cc] += r0 * xv.x + r1 * xv.y + r2 * xv.z + r3 * xv.w;
    }
  }

  const int i = t;
  int j = 0;
  for (; j + 3 <= i; j += 4) {
    float k0 = kl[i - j], k1 = kl[i - j - 1], k2 = kl[i - j - 2],
          k3 = kl[i - j - 3];
#pragma unroll
    for (int cc = 0; cc < 8; ++cc) {
      const float4 uv = *(const float4*)&us[cc * MC + j];
      acc[cc] += k0 * uv.x + k1 * uv.y + k2 * uv.z + k3 * uv.w;
    }
  }
  for (; j <= i; ++j) {
    float kv = kl[i - j];
#pragma unroll
    for (int cc = 0; cc < 8; ++cc) acc[cc] += kv * us[cc * MC + j];
  }

  const float D0 = Dv[0];
#pragma unroll
  for (int cc = 0; cc < 8; ++cc)
    out[(size_t)(c0 + cc) * MC + i] = acc[cc] + D0 * us[cc * MC + i];
}

// ---------------------------------------------------------------------
extern "C" void kernel_launch(void* const* d_in, const int* in_sizes, int n_in,
                              void* d_out, int out_size, void* d_ws,
                              size_t ws_size, hipStream_t stream) {
  (void)in_sizes; (void)n_in; (void)out_size; (void)ws_size;
  const float* u = (const float*)d_in[0];
  const float* A = (const float*)d_in[1];
  const float* B = (const float*)d_in[2];
  const float* C = (const float*)d_in[3];
  const float* D = (const float*)d_in[4];
  const float* ls = (const float*)d_in[5];
  float* ws = (float*)d_ws;  // needs WS_FLOATS*4 ~ 4.35 MB
  float* out = (float*)d_out;

  hipLaunchKernelGGL(k_setup, dim3(1), dim3(1024), 0, stream, A, B, C, ls, ws);
  hipLaunchKernelGGL(k_f, dim3(NCHUNK / 16), dim3(256), 0, stream, u, ws);
  hipLaunchKernelGGL(k_scan1, dim3(NSEG), dim3(64), 0, stream, ws);
  hipLaunchKernelGGL(k_scantop, dim3(1), dim3(64), 0, stream, ws);
  hipLaunchKernelGGL(k_scan2, dim3(NSEG), dim3(64), 0, stream, ws);
  hipLaunchKernelGGL(k_final, dim3(NCHUNK / 8), dim3(256), 0, stream, u, D, ws,
                     out);
}

// Round 6
// 402.877 us; speedup vs baseline: 1.1024x; 1.0628x over previous
//
#include <hip/hip_runtime.h>
#include <cmath>

// =====================================================================
// S4-style SSM layer, N=64, L=2^22, as an EXACT chunked linear recurrence.
//   x[t] = Ab x[t-1] + Bb u[t],  y[t] = Cb x[t] + D u[t]
// Pipeline:
//   k_setup : GJ on [I-hA | I+hA | 2hB] (LDS float4, stride 148 = 37 quads,
//             bank-spread) -> Ab,Bb; 15 dual squarings in LDS (2 waves);
//             X/R chains (8 waves x 32 steps, matrix rows in registers,
//             readlane broadcast); Rt transpose; Kloc. (1 block, 512 thr)
//   k_f     : F[c][n] = sum_j Xcol[MC-1-j][n] u[c*MC+j]
//   k_scan1 : per-segment scan (from 0) -> segment carries
//   k_scantop: top-level scan over segments with Ab^(2^15)
//   k_scan2 : re-scan seeded; F[] becomes Xinit[c]
//   k_final : y = Rt.Xinit + tri-conv(Kloc,u) + D*u
// Scans: 8-deep global prefetch (HBM ~900cy >> 1-step lookahead).
// =====================================================================

#define MC 256
#define LSEQ 4194304
#define NCHUNK (LSEQ / MC)   // 16384
#define SEG 128
#define NSEG (NCHUNK / SEG)  // 128

// ---- workspace layout (float offsets), ~4.34 MB
#define ABR_OFF 0                            // Ab rows [64][64]
#define ABT_OFF 4096                         // Ab^T rows
#define P5R_OFF 8192                         // Ab^32 rows
#define P5T_OFF 12288                        // (Ab^32)^T rows
#define P8R_OFF 16384                        // Ab^256 rows
#define P15_OFF 20480                        // Ab^32768 rows
#define BB_OFF 24576                         // Bb [64]
#define KL_OFF 24640                         // Kloc [256]
#define XCOL_OFF 24896                       // Xcol[i*64+n]
#define RTT_OFF 41280                        // Rtt[i*64+n] (scratch)
#define RT_OFF 57664                         // Rt[n*MC+i]
#define F_OFF 74048                          // F[c*64+n] (later Xinit)
#define CARRY_OFF (F_OFF + NCHUNK * 64)      // 1122624
#define SEGINIT_OFF (CARRY_OFF + NSEG * 64)  // 1130816
#define WS_FLOATS (SEGINIT_OFF + NSEG * 64)  // 1139008

__device__ __forceinline__ float bcast(float x, int k) {
  return __int_as_float(__builtin_amdgcn_readlane(__float_as_int(x), k));
}

// x' = M x, lane n = row n; M rows in registers (m[kq] = row cols 4kq..4kq+3)
__device__ __forceinline__ float matvec64(const float4 (&m)[16], float x) {
  float a0 = 0.f, a1 = 0.f, a2 = 0.f, a3 = 0.f;
#pragma unroll
  for (int kq = 0; kq < 16; ++kq) {
    a0 = fmaf(m[kq].x, bcast(x, 4 * kq + 0), a0);
    a1 = fmaf(m[kq].y, bcast(x, 4 * kq + 1), a1);
    a2 = fmaf(m[kq].z, bcast(x, 4 * kq + 2), a2);
    a3 = fmaf(m[kq].w, bcast(x, 4 * kq + 3), a3);
  }
  return ((a0 + a1) + (a2 + a3));
}

__device__ __forceinline__ void load_rows(float4 (&m)[16], const float* src,
                                          int lane) {
#pragma unroll
  for (int kq = 0; kq < 16; ++kq)
    m[kq] = *(const float4*)(src + lane * 64 + kq * 4);
}

#define CGET(v, cj) \
  ((cj) == 0 ? (v).x : (cj) == 1 ? (v).y : (cj) == 2 ? (v).z : (v).w)

// ---------------------------------------------------------------------
// K1: one-block setup, 512 threads (2 waves/SIMD -> 256-VGPR cap so the
// chain phases' float4 m[16] stays register-resident; round-3's 1024-thr
// version reported VGPR_Count=52 => spilled).
// LDS map (floats):
//   GJ: G[64][148] = [0,9472) ; colbuf @13440
//   post-GJ: AR[64][64] @0, AT @4096, tr[64][65] @8192,
//            xs(8*68) @12352, rs(8*68) @12896
// ---------------------------------------------------------------------
__global__ __launch_bounds__(512) void k_setup(
    const float* __restrict__ A, const float* __restrict__ Bv,
    const float* __restrict__ Cv, const float* __restrict__ lstep,
    float* __restrict__ ws) {
  __shared__ __align__(16) float sm[13504];
  float* xs = sm + 12352;
  float* rs = sm + 12896;
  float* colbuf = sm + 13440;
  const int t = threadIdx.x;
  const int w = t >> 6, lane = t & 63;
  const float h = 0.5f * expf(lstep[0]);  // step/2

  // ---- P1: fill G = [I-hA | I+hA | 2hB | pad], row stride 148 floats.
  for (int idx = t; idx < 64 * 148; idx += 512) {
    int r = idx / 148, c = idx - r * 148;
    float v = 0.f;
    if (c < 64)
      v = (r == c ? 1.0f : 0.0f) - h * A[r * 64 + c];
    else if (c < 128)
      v = (r == (c - 64) ? 1.0f : 0.0f) + h * A[r * 64 + (c - 64)];
    else if (c == 128)
      v = 2.0f * h * Bv[r];
    sm[idx] = v;
  }
  __syncthreads();
  // ---- Gauss-Jordan, no pivoting (strongly diagonally dominant).
  // Each wave owns quads q = (k>>2)+w mod 8; lanes = rows. Stride 37 quads
  // => lanes spread over all 8 four-bank groups (conflict-free b128).
  {
    float4* G4 = (float4*)sm;  // row stride 37 quads
    for (int k = 0; k < 64; ++k) {
      if (t < 64) colbuf[t] = sm[t * 148 + k];  // pre-step column k
      __syncthreads();
      const float pinv = 1.0f / colbuf[k];
      const int r = lane;
      const float mr = colbuf[r] * pinv;
      for (int q = (k >> 2) + w; q <= 32; q += 8) {
        float4 pr = G4[k * 37 + q];
        float4 g = G4[r * 37 + q];
        if (r == k) {
          g.x = pr.x * pinv; g.y = pr.y * pinv;
          g.z = pr.z * pinv; g.w = pr.w * pinv;
        } else {
          g.x = fmaf(-mr, pr.x, g.x); g.y = fmaf(-mr, pr.y, g.y);
          g.z = fmaf(-mr, pr.z, g.z); g.w = fmaf(-mr, pr.w, g.w);
        }
        G4[r * 37 + q] = g;
      }
      __syncthreads();
    }
  }
  // export Ab (cols 64..127) and Bb (col 128)
  for (int idx = t; idx < 4096; idx += 512) {
    int r = idx >> 6, c = idx & 63;
    ws[ABR_OFF + idx] = sm[r * 148 + 64 + c];
  }
  if (t < 64) ws[BB_OFF + t] = sm[t * 148 + 128];
  __syncthreads();  // G dead after this point

  // ---- build AR (rows) + AT (cols-as-rows) in LDS; export ABT
  {
    float* AR = sm;          // [64][64]
    float* AT = sm + 4096;   // [64][64]
    float* tr = sm + 8192;   // [64][65]
    for (int idx = t; idx < 4096; idx += 512) {
      float v = ws[ABR_OFF + idx];
      AR[idx] = v;
      tr[(idx & 63) * 65 + (idx >> 6)] = v;  // tr[c][r]
    }
    __syncthreads();
    for (int idx = t; idx < 4096; idx += 512) {
      float v = tr[(idx >> 6) * 65 + (idx & 63)];
      AT[idx] = v;
      ws[ABT_OFF + idx] = v;
    }
  }
  __syncthreads();

  // ---- P3: 15 in-place dual squarings (AR=rows, AT=cols), 2 waves,
  //      8x4 register tiles; b/a reads are 16-address broadcasts.
  {
    float4* AR4 = (float4*)sm;           // [64][16] quads
    float4* AT4 = (float4*)(sm + 4096);  // [64][16] quads
    const bool active = t < 128;
    const int r0 = (t >> 4) << 3;  // 0..56 for t<128
    const int c0q = t & 15;
#pragma unroll 1
    for (int s = 1; s <= 15; ++s) {
      float4 acc[8];
#pragma unroll
      for (int j = 0; j < 8; ++j) acc[j] = {0.f, 0.f, 0.f, 0.f};
      if (active) {
#pragma unroll 8
        for (int k = 0; k < 64; ++k) {
          const float4 b = AR4[k * 16 + c0q];
          const float4 a0 = AT4[k * 16 + (r0 >> 2)];
          const float4 a1 = AT4[k * 16 + (r0 >> 2) + 1];
          acc[0].x = fmaf(a0.x, b.x, acc[0].x); acc[0].y = fmaf(a0.x, b.y, acc[0].y);
          acc[0].z = fmaf(a0.x, b.z, acc[0].z); acc[0].w = fmaf(a0.x, b.w, acc[0].w);
          acc[1].x = fmaf(a0.y, b.x, acc[1].x); acc[1].y = fmaf(a0.y, b.y, acc[1].y);
          acc[1].z = fmaf(a0.y, b.z, acc[1].z); acc[1].w = fmaf(a0.y, b.w, acc[1].w);
          acc[2].x = fmaf(a0.z, b.x, acc[2].x); acc[2].y = fmaf(a0.z, b.y, acc[2].y);
          acc[2].z = fmaf(a0.z, b.z, acc[2].z); acc[2].w = fmaf(a0.z, b.w, acc[2].w);
          acc[3].x = fmaf(a0.w, b.x, acc[3].x); acc[3].y = fmaf(a0.w, b.y, acc[3].y);
          acc[3].z = fmaf(a0.w, b.z, acc[3].z); acc[3].w = fmaf(a0.w, b.w, acc[3].w);
          acc[4].x = fmaf(a1.x, b.x, acc[4].x); acc[4].y = fmaf(a1.x, b.y, acc[4].y);
          acc[4].z = fmaf(a1.x, b.z, acc[4].z); acc[4].w = fmaf(a1.x, b.w, acc[4].w);
          acc[5].x = fmaf(a1.y, b.x, acc[5].x); acc[5].y = fmaf(a1.y, b.y, acc[5].y);
          acc[5].z = fmaf(a1.y, b.z, acc[5].z); acc[5].w = fmaf(a1.y, b.w, acc[5].w);
          acc[6].x = fmaf(a1.z, b.x, acc[6].x); acc[6].y = fmaf(a1.z, b.y, acc[6].y);
          acc[6].z = fmaf(a1.z, b.z, acc[6].z); acc[6].w = fmaf(a1.z, b.w, acc[6].w);
          acc[7].x = fmaf(a1.w, b.x, acc[7].x); acc[7].y = fmaf(a1.w, b.y, acc[7].y);
          acc[7].z = fmaf(a1.w, b.z, acc[7].z); acc[7].w = fmaf(a1.w, b.w, acc[7].w);
        }
      }
      __syncthreads();  // ALL reads of AR/AT complete before overwrite
      if (active) {
#pragma unroll
        for (int j = 0; j < 8; ++j) AR4[(r0 + j) * 16 + c0q] = acc[j];
#pragma unroll
        for (int cj = 0; cj < 4; ++cj) {
          float4 lo = {CGET(acc[0], cj), CGET(acc[1], cj), CGET(acc[2], cj),
                       CGET(acc[3], cj)};
          float4 hi = {CGET(acc[4], cj), CGET(acc[5], cj), CGET(acc[6], cj),
                       CGET(acc[7], cj)};
          AT4[(4 * c0q + cj) * 16 + (r0 >> 2)] = lo;
          AT4[(4 * c0q + cj) * 16 + (r0 >> 2) + 1] = hi;
          if (s == 5) {
            *(float4*)&ws[P5T_OFF + (4 * c0q + cj) * 64 + r0] = lo;
            *(float4*)&ws[P5T_OFF + (4 * c0q + cj) * 64 + r0 + 4] = hi;
          }
        }
        if (s == 5 || s == 8 || s == 15) {
          const int off = (s == 5) ? P5R_OFF : (s == 8) ? P8R_OFF : P15_OFF;
#pragma unroll
          for (int j = 0; j < 8; ++j)
            *(float4*)&ws[off + (r0 + j) * 64 + 4 * c0q] = acc[j];
        }
      }
      __syncthreads();
    }
  }

  // ---- P4a: seeds. wave0: x_g=(Ab^32)^g Bb; wave1: r_g=(AbT^32)^g (AbT c)
  if (w == 0) {
    float4 m[16];
    load_rows(m, ws + P5R_OFF, lane);
    float x = ws[BB_OFF + lane];
    xs[0 * 68 + lane] = x;
#pragma unroll 1
    for (int g = 1; g < 8; ++g) {
      x = matvec64(m, x);
      xs[g * 68 + lane] = x;
    }
  } else if (w == 1) {
    float4 m[16];
    load_rows(m, ws + ABT_OFF, lane);
    float r = matvec64(m, Cv[lane]);  // Rtt[0] = Ab^T c
    load_rows(m, ws + P5T_OFF, lane);
    rs[0 * 68 + lane] = r;
#pragma unroll 1
    for (int g = 1; g < 8; ++g) {
      r = matvec64(m, r);
      rs[g * 68 + lane] = r;
    }
  }
  __syncthreads();

  // ---- P4b: X chains, 8 waves x 32 steps: Xcol[32w+j] = Ab^(32w+j) Bb
  {
    float4 m[16];
    load_rows(m, ws + ABR_OFF, lane);
    float x = xs[w * 68 + lane];
#pragma unroll 1
    for (int j = 0; j < 32; ++j) {
      ws[XCOL_OFF + (32 * w + j) * 64 + lane] = x;
      if (j < 31) x = matvec64(m, x);
    }
  }
  // ---- P4c: R chains: Rtt[32w+j] = (AbT)^(32w+j+1) c
  {
    float4 m[16];
    load_rows(m, ws + ABT_OFF, lane);
    float r = rs[w * 68 + lane];
#pragma unroll 1
    for (int j = 0; j < 32; ++j) {
      ws[RTT_OFF + (32 * w + j) * 64 + lane] = r;
      if (j < 31) r = matvec64(m, r);
    }
  }
  __syncthreads();

  // ---- P4d: transpose Rtt[i][n] -> Rt[n][MC]
  {
    float* tr = sm + 8192;  // [64][65]
    for (int blk = 0; blk < 4; ++blk) {
      for (int idx = t; idx < 4096; idx += 512) {
        int il = idx >> 6, nn = idx & 63;
        tr[nn * 65 + il] = ws[RTT_OFF + (blk * 64 + il) * 64 + nn];
      }
      __syncthreads();
      for (int idx = t; idx < 4096; idx += 512) {
        int nn = idx >> 6, il = idx & 63;
        ws[RT_OFF + nn * MC + blk * 64 + il] = tr[nn * 65 + il];
      }
      __syncthreads();
    }
  }

  // ---- P5: Kloc[i] = Cb . Xcol[i]  (shuffle reduce)
  {
    const float cv = Cv[lane];
    for (int i = w; i < MC; i += 8) {
      float p = cv * ws[XCOL_OFF + i * 64 + lane];
#pragma unroll
      for (int m = 32; m >= 1; m >>= 1) p += __shfl_xor(p, m, 64);
      if (lane == 0) ws[KL_OFF + i] = p;
    }
  }
}

// ---------------------------------------------------------------------
// K2: F[c][n] = sum_j Xcol[MC-1-j][n] * u[c*MC+j]. 16 chunks per block.
// ---------------------------------------------------------------------
__global__ __launch_bounds__(256) void k_f(const float* __restrict__ u,
                                           float* __restrict__ ws) {
  __shared__ __align__(16) float us[16 * MC];
  const int t = threadIdx.x;
  const int c0 = blockIdx.x * 16;
  for (int idx = t; idx < 16 * MC; idx += 256)
    us[idx] = u[(size_t)c0 * MC + idx];
  __syncthreads();
  const int n = t & 63, g = t >> 6;  // wave g owns chunks c0+4g..c0+4g+3
  const float* xc = ws + XCOL_OFF;
  const float* ug = us + g * 4 * MC;
  float a0 = 0.f, a1 = 0.f, a2 = 0.f, a3 = 0.f;
  for (int j = 0; j < MC; j += 4) {
    float x0 = xc[(MC - 1 - j) * 64 + n];
    float x1 = xc[(MC - 2 - j) * 64 + n];
    float x2 = xc[(MC - 3 - j) * 64 + n];
    float x3 = xc[(MC - 4 - j) * 64 + n];
    {
      const float4 uv = *(const float4*)&ug[0 * MC + j];
      a0 += x0 * uv.x + x1 * uv.y + x2 * uv.z + x3 * uv.w;
    }
    {
      const float4 uv = *(const float4*)&ug[1 * MC + j];
      a1 += x0 * uv.x + x1 * uv.y + x2 * uv.z + x3 * uv.w;
    }
    {
      const float4 uv = *(const float4*)&ug[2 * MC + j];
      a2 += x0 * uv.x + x1 * uv.y + x2 * uv.z + x3 * uv.w;
    }
    {
      const float4 uv = *(const float4*)&ug[3 * MC + j];
      a3 += x0 * uv.x + x1 * uv.y + x2 * uv.z + x3 * uv.w;
    }
  }
  float* Fb = ws + F_OFF + (c0 + g * 4) * 64;
  Fb[0 * 64 + n] = a0;
  Fb[1 * 64 + n] = a1;
  Fb[2 * 64 + n] = a2;
  Fb[3 * 64 + n] = a3;
}

// ---------------------------------------------------------------------
// Scan kernels: one wave scans (P rows in regs, readlane bcast), 8-deep
// global prefetch; an extra wave helps load the P matrix then exits.
// ---------------------------------------------------------------------
#define MATVEC_STEP(preg, xv, a0, a1, a2, a3)          \
  _Pragma("unroll") for (int k = 0; k < 64; k += 4) {  \
    a0 = fmaf(preg[k + 0], bcast(xv, k + 0), a0);      \
    a1 = fmaf(preg[k + 1], bcast(xv, k + 1), a1);      \
    a2 = fmaf(preg[k + 2], bcast(xv, k + 2), a2);      \
    a3 = fmaf(preg[k + 3], bcast(xv, k + 3), a3);      \
  }

__global__ __launch_bounds__(128) void k_scan1(float* __restrict__ ws) {
  __shared__ float Pl[4160];
  const int t = threadIdx.x;
  for (int idx = t; idx < 4096; idx += 128)
    Pl[(idx >> 6) * 65 + (idx & 63)] = ws[P8R_OFF + idx];
  __syncthreads();
  if (t >= 64) return;
  const int n = t;
  float p[64];
#pragma unroll
  for (int k = 0; k < 64; ++k) p[k] = Pl[n * 65 + k];
  float x = 0.f;
  const float* Fp = ws + F_OFF + blockIdx.x * SEG * 64;
  float fc[8], fn[8];
#pragma unroll
  for (int i = 0; i < 8; ++i) fc[i] = Fp[i * 64 + n];
  for (int c0 = 0; c0 < SEG; c0 += 8) {
#pragma unroll
    for (int i = 0; i < 8; ++i) {
      int cn = c0 + 8 + i;
      if (cn > SEG - 1) cn = SEG - 1;
      fn[i] = Fp[cn * 64 + n];
    }
#pragma unroll
    for (int i = 0; i < 8; ++i) {
      float a0 = 0.f, a1 = 0.f, a2 = 0.f, a3 = 0.f;
      MATVEC_STEP(p, x, a0, a1, a2, a3)
      x = ((a0 + a1) + (a2 + a3)) + fc[i];
    }
#pragma unroll
    for (int i = 0; i < 8; ++i) fc[i] = fn[i];
  }
  ws[CARRY_OFF + blockIdx.x * 64 + n] = x;
}

__global__ __launch_bounds__(128) void k_scantop(float* __restrict__ ws) {
  __shared__ float Ql[4160];
  const int t = threadIdx.x;
  for (int idx = t; idx < 4096; idx += 128)
    Ql[(idx >> 6) * 65 + (idx & 63)] = ws[P15_OFF + idx];
  __syncthreads();
  if (t >= 64) return;
  const int n = t;
  float q[64];
#pragma unroll
  for (int k = 0; k < 64; ++k) q[k] = Ql[n * 65 + k];
  float x = 0.f;
  float fc[8], fn[8];
#pragma unroll
  for (int i = 0; i < 8; ++i) fc[i] = ws[CARRY_OFF + i * 64 + n];
  for (int s0 = 0; s0 < NSEG; s0 += 8) {
#pragma unroll
    for (int i = 0; i < 8; ++i) {
      int sn = s0 + 8 + i;
      if (sn > NSEG - 1) sn = NSEG - 1;
      fn[i] = ws[CARRY_OFF + sn * 64 + n];
    }
#pragma unroll
    for (int i = 0; i < 8; ++i) {
      ws[SEGINIT_OFF + (s0 + i) * 64 + n] = x;  // exclusive prefix state
      float a0 = 0.f, a1 = 0.f, a2 = 0.f, a3 = 0.f;
      MATVEC_STEP(q, x, a0, a1, a2, a3)
      x = ((a0 + a1) + (a2 + a3)) + fc[i];
    }
#pragma unroll
    for (int i = 0; i < 8; ++i) fc[i] = fn[i];
  }
}

__global__ __launch_bounds__(128) void k_scan2(float* __restrict__ ws) {
  __shared__ float Pl[4160];
  const int t = threadIdx.x;
  for (int idx = t; idx < 4096; idx += 128)
    Pl[(idx >> 6) * 65 + (idx & 63)] = ws[P8R_OFF + idx];
  __syncthreads();
  if (t >= 64) return;
  const int n = t;
  float p[64];
#pragma unroll
  for (int k = 0; k < 64; ++k) p[k] = Pl[n * 65 + k];
  float x = ws[SEGINIT_OFF + blockIdx.x * 64 + n];
  float* Fp = ws + F_OFF + blockIdx.x * SEG * 64;
  float fc[8], fn[8];
#pragma unroll
  for (int i = 0; i < 8; ++i) fc[i] = Fp[i * 64 + n];
  for (int c0 = 0; c0 < SEG; c0 += 8) {
#pragma unroll
    for (int i = 0; i < 8; ++i) {
      int cn = c0 + 8 + i;
      if (cn > SEG - 1) cn = SEG - 1;
      fn[i] = Fp[cn * 64 + n];
    }
#pragma unroll
    for (int i = 0; i < 8; ++i) {
      float fv = fc[i];
      Fp[(c0 + i) * 64 + n] = x;  // F becomes Xinit[c] (state BEFORE chunk)
      float a0 = 0.f, a1 = 0.f, a2 = 0.f, a3 = 0.f;
      MATVEC_STEP(p, x, a0, a1, a2, a3)
      x = ((a0 + a1) + (a2 + a3)) + fv;
    }
#pragma unroll
    for (int i = 0; i < 8; ++i) fc[i] = fn[i];
  }
}

// ---------------------------------------------------------------------
// K6: y[c*MC+i] = Rt[:,i].Xinit[c] + tri-conv(Kloc,u) + D*u. 8 chunks/blk.
// ---------------------------------------------------------------------
__global__ __launch_bounds__(256) void k_final(const float* __restrict__ u,
                                               const float* __restrict__ Dv,
                                               const float* __restrict__ ws,
                                               float* __restrict__ out) {
  __shared__ __align__(16) float us[8 * MC];
  __shared__ __align__(16) float kl[MC];
  __shared__ __align__(16) float xin[8 * 64];
  const int t = threadIdx.x;
  const int c0 = blockIdx.x * 8;
  for (int idx = t; idx < 8 * MC; idx += 256)
    us[idx] = u[(size_t)c0 * MC + idx];
  kl[t] = ws[KL_OFF + t];
  for (int idx = t; idx < 8 * 64; idx += 256)
    xin[idx] = ws[F_OFF + c0 * 64 + idx];
  __syncthreads();

  float acc[8];
#pragma unroll
  for (int cc = 0; cc < 8; ++cc) acc[cc] = 0.f;

  const float* rt = ws + RT_OFF;
#pragma unroll 4
  for (int nn = 0; nn < 64; nn += 4) {
    float r0 = rt[(nn + 0) * MC + t];
    float r1 = rt[(nn + 1) * MC + t];
    float r2 = rt[(nn + 2) * MC + t];
    float r3 = rt[(nn + 3) * MC + t];
#pragma unroll
    for (int cc = 0; cc < 8; ++cc) {
      const float4 xv = *(const float4*)&xin[cc * 64 + nn];
      acc[cc] += r0 * xv.x + r1 * xv.y + r2 * xv.z + r3 * xv.w;
    }
  }

  const int i = t;
  int j = 0;
  for (; j + 3 <= i; j += 4) {
    float k0 = kl[i - j], k1 = kl[i - j - 1], k2 = kl[i - j - 2],
          k3 = kl[i - j - 3];
#pragma unroll
    for (int cc = 0; cc < 8; ++cc) {
      const float4 uv = *(const float4*)&us[cc * MC + j];
      acc[cc] += k0 * uv.x + k1 * uv.y + k2 * uv.z + k3 * uv.w;
    }
  }
  for (; j <= i; ++j) {
    float kv = kl[i - j];
#pragma unroll
    for (int cc = 0; cc < 8; ++cc) acc[cc] += kv * us[cc * MC + j];
  }

  const float D0 = Dv[0];
#pragma unroll
  for (int cc = 0; cc < 8; ++cc)
    out[(size_t)(c0 + cc) * MC + i] = acc[cc] + D0 * us[cc * MC + i];
}

// ---------------------------------------------------------------------
extern "C" void kernel_launch(void* const* d_in, const int* in_sizes, int n_in,
                              void* d_out, int out_size, void* d_ws,
                              size_t ws_size, hipStream_t stream) {
  (void)in_sizes; (void)n_in; (void)out_size; (void)ws_size;
  const float* u = (const float*)d_in[0];
  const float* A = (const float*)d_in[1];
  const float* B = (const float*)d_in[2];
  const float* C = (const float*)d_in[3];
  const float* D = (const float*)d_in[4];
  const float* ls = (const float*)d_in[5];
  float* ws = (float*)d_ws;  // needs WS_FLOATS*4 ~ 4.34 MB
  float* out = (float*)d_out;

  hipLaunchKernelGGL(k_setup, dim3(1), dim3(512), 0, stream, A, B, C, ls, ws);
  hipLaunchKernelGGL(k_f, dim3(NCHUNK / 16), dim3(256), 0, stream, u, ws);
  hipLaunchKernelGGL(k_scan1, dim3(NSEG), dim3(128), 0, stream, ws);
  hipLaunchKernelGGL(k_scantop, dim3(1), dim3(128), 0, stream, ws);
  hipLaunchKernelGGL(k_scan2, dim3(NSEG), dim3(128), 0, stream, ws);
  hipLaunchKernelGGL(k_final, dim3(NCHUNK / 8), dim3(256), 0, stream, u, D, ws,
                     out);
}

// Round 9
// 400.787 us; speedup vs baseline: 1.1082x; 1.0052x over previous
//
#include <hip/hip_runtime.h>
#include <cmath>

// =====================================================================
// S4-style SSM layer, N=64, L=2^22, as an EXACT chunked linear recurrence.
//   x[t] = Ab x[t-1] + Bb u[t],  y[t] = Cb x[t] + D u[t]
// Pipeline:
//   k_setup : GJ on [I-hA | I+hA | 2hB] (LDS float4, stride 148 = 37 quads,
//             bank-spread) -> Ab,Bb; 15 dual squarings in LDS (2 waves);
//             X/R chains (8 waves x 32 steps, matrix rows in registers,
//             readlane broadcast); Rt transpose; Kloc. (1 block, 512 thr)
//   k_f     : F[c][n] = sum_j Xcol[MC-1-j][n] u[c*MC+j]
//   k_scan1 : per-segment scan (from 0) -> segment carries
//   k_scantop: top-level scan over segments with Ab^(2^15)
//   k_scan2 : re-scan seeded; F[] becomes Xinit[c]
//   k_final : y = Rt.Xinit + tri-conv(Kloc,u) + D*u
// REGISTER BUDGET (round-6 lesson): without a 2nd __launch_bounds__ arg
// the allocator targets full occupancy -> 64-VGPR cap -> float4 m[16]
// (64 VGPRs) and scan p[64] SPILL. k_setup uses (512,1) => 256-VGPR cap;
// scans use (128,1). Verified via VGPR_Count in the dispatch CSV.
// =====================================================================

#define MC 256
#define LSEQ 4194304
#define NCHUNK (LSEQ / MC)   // 16384
#define SEG 128
#define NSEG (NCHUNK / SEG)  // 128

// ---- workspace layout (float offsets), ~4.34 MB
#define ABR_OFF 0                            // Ab rows [64][64]
#define ABT_OFF 4096                         // Ab^T rows
#define P5R_OFF 8192                         // Ab^32 rows
#define P5T_OFF 12288                        // (Ab^32)^T rows
#define P8R_OFF 16384                        // Ab^256 rows
#define P15_OFF 20480                        // Ab^32768 rows
#define BB_OFF 24576                         // Bb [64]
#define KL_OFF 24640                         // Kloc [256]
#define XCOL_OFF 24896                       // Xcol[i*64+n]
#define RTT_OFF 41280                        // Rtt[i*64+n] (scratch)
#define RT_OFF 57664                         // Rt[n*MC+i]
#define F_OFF 74048                          // F[c*64+n] (later Xinit)
#define CARRY_OFF (F_OFF + NCHUNK * 64)      // 1122624
#define SEGINIT_OFF (CARRY_OFF + NSEG * 64)  // 1130816
#define WS_FLOATS (SEGINIT_OFF + NSEG * 64)  // 1139008

__device__ __forceinline__ float bcast(float x, int k) {
  return __int_as_float(__builtin_amdgcn_readlane(__float_as_int(x), k));
}

// x' = M x, lane n = row n; M rows in registers (m[kq] = row cols 4kq..4kq+3)
__device__ __forceinline__ float matvec64(const float4 (&m)[16], float x) {
  float a0 = 0.f, a1 = 0.f, a2 = 0.f, a3 = 0.f;
#pragma unroll
  for (int kq = 0; kq < 16; ++kq) {
    a0 = fmaf(m[kq].x, bcast(x, 4 * kq + 0), a0);
    a1 = fmaf(m[kq].y, bcast(x, 4 * kq + 1), a1);
    a2 = fmaf(m[kq].z, bcast(x, 4 * kq + 2), a2);
    a3 = fmaf(m[kq].w, bcast(x, 4 * kq + 3), a3);
  }
  return ((a0 + a1) + (a2 + a3));
}

__device__ __forceinline__ void load_rows(float4 (&m)[16], const float* src,
                                          int lane) {
#pragma unroll
  for (int kq = 0; kq < 16; ++kq)
    m[kq] = *(const float4*)(src + lane * 64 + kq * 4);
}

#define CGET(v, cj) \
  ((cj) == 0 ? (v).x : (cj) == 1 ? (v).y : (cj) == 2 ? (v).z : (v).w)

// ---------------------------------------------------------------------
// K1: one-block setup, 512 threads, min-waves/EU = 1 -> 256-VGPR cap
// (2 waves/SIMD must co-reside). The chain phases' float4 m[16] is then
// register-resident instead of occupancy-capped at 64 VGPRs + spill.
// LDS map (floats):
//   GJ: G[64][148] = [0,9472) ; colbuf @13440
//   post-GJ: AR[64][64] @0, AT @4096, tr[64][65] @8192,
//            xs(8*68) @12352, rs(8*68) @12896
// ---------------------------------------------------------------------
__global__ __launch_bounds__(512, 1) void k_setup(
    const float* __restrict__ A, const float* __restrict__ Bv,
    const float* __restrict__ Cv, const float* __restrict__ lstep,
    float* __restrict__ ws) {
  __shared__ __align__(16) float sm[13504];
  float* xs = sm + 12352;
  float* rs = sm + 12896;
  float* colbuf = sm + 13440;
  const int t = threadIdx.x;
  const int w = t >> 6, lane = t & 63;
  const float h = 0.5f * expf(lstep[0]);  // step/2

  // ---- P1: fill G = [I-hA | I+hA | 2hB | pad], row stride 148 floats.
  for (int idx = t; idx < 64 * 148; idx += 512) {
    int r = idx / 148, c = idx - r * 148;
    float v = 0.f;
    if (c < 64)
      v = (r == c ? 1.0f : 0.0f) - h * A[r * 64 + c];
    else if (c < 128)
      v = (r == (c - 64) ? 1.0f : 0.0f) + h * A[r * 64 + (c - 64)];
    else if (c == 128)
      v = 2.0f * h * Bv[r];
    sm[idx] = v;
  }
  __syncthreads();
  // ---- Gauss-Jordan, no pivoting (strongly diagonally dominant).
  // Each wave owns quads q = (k>>2)+w mod 8; lanes = rows. Stride 37 quads
  // => lanes spread over all 8 four-bank groups (conflict-free b128).
  {
    float4* G4 = (float4*)sm;  // row stride 37 quads
    for (int k = 0; k < 64; ++k) {
      if (t < 64) colbuf[t] = sm[t * 148 + k];  // pre-step column k
      __syncthreads();
      const float pinv = 1.0f / colbuf[k];
      const int r = lane;
      const float mr = colbuf[r] * pinv;
      for (int q = (k >> 2) + w; q <= 32; q += 8) {
        float4 pr = G4[k * 37 + q];
        float4 g = G4[r * 37 + q];
        if (r == k) {
          g.x = pr.x * pinv; g.y = pr.y * pinv;
          g.z = pr.z * pinv; g.w = pr.w * pinv;
        } else {
          g.x = fmaf(-mr, pr.x, g.x); g.y = fmaf(-mr, pr.y, g.y);
          g.z = fmaf(-mr, pr.z, g.z); g.w = fmaf(-mr, pr.w, g.w);
        }
        G4[r * 37 + q] = g;
      }
      __syncthreads();
    }
  }
  // export Ab (cols 64..127) and Bb (col 128)
  for (int idx = t; idx < 4096; idx += 512) {
    int r = idx >> 6, c = idx & 63;
    ws[ABR_OFF + idx] = sm[r * 148 + 64 + c];
  }
  if (t < 64) ws[BB_OFF + t] = sm[t * 148 + 128];
  __syncthreads();  // G dead after this point

  // ---- build AR (rows) + AT (cols-as-rows) in LDS; export ABT
  {
    float* AR = sm;          // [64][64]
    float* AT = sm + 4096;   // [64][64]
    float* tr = sm + 8192;   // [64][65]
    for (int idx = t; idx < 4096; idx += 512) {
      float v = ws[ABR_OFF + idx];
      AR[idx] = v;
      tr[(idx & 63) * 65 + (idx >> 6)] = v;  // tr[c][r]
    }
    __syncthreads();
    for (int idx = t; idx < 4096; idx += 512) {
      float v = tr[(idx >> 6) * 65 + (idx & 63)];
      AT[idx] = v;
      ws[ABT_OFF + idx] = v;
    }
  }
  __syncthreads();

  // ---- P3: 15 in-place dual squarings (AR=rows, AT=cols), 2 waves,
  //      8x4 register tiles; b/a reads are 16-address broadcasts.
  {
    float4* AR4 = (float4*)sm;           // [64][16] quads
    float4* AT4 = (float4*)(sm + 4096);  // [64][16] quads
    const bool active = t < 128;
    const int r0 = (t >> 4) << 3;  // 0..56 for t<128
    const int c0q = t & 15;
#pragma unroll 1
    for (int s = 1; s <= 15; ++s) {
      float4 acc[8];
#pragma unroll
      for (int j = 0; j < 8; ++j) acc[j] = {0.f, 0.f, 0.f, 0.f};
      if (active) {
#pragma unroll 8
        for (int k = 0; k < 64; ++k) {
          const float4 b = AR4[k * 16 + c0q];
          const float4 a0 = AT4[k * 16 + (r0 >> 2)];
          const float4 a1 = AT4[k * 16 + (r0 >> 2) + 1];
          acc[0].x = fmaf(a0.x, b.x, acc[0].x); acc[0].y = fmaf(a0.x, b.y, acc[0].y);
          acc[0].z = fmaf(a0.x, b.z, acc[0].z); acc[0].w = fmaf(a0.x, b.w, acc[0].w);
          acc[1].x = fmaf(a0.y, b.x, acc[1].x); acc[1].y = fmaf(a0.y, b.y, acc[1].y);
          acc[1].z = fmaf(a0.y, b.z, acc[1].z); acc[1].w = fmaf(a0.y, b.w, acc[1].w);
          acc[2].x = fmaf(a0.z, b.x, acc[2].x); acc[2].y = fmaf(a0.z, b.y, acc[2].y);
          acc[2].z = fmaf(a0.z, b.z, acc[2].z); acc[2].w = fmaf(a0.z, b.w, acc[2].w);
          acc[3].x = fmaf(a0.w, b.x, acc[3].x); acc[3].y = fmaf(a0.w, b.y, acc[3].y);
          acc[3].z = fmaf(a0.w, b.z, acc[3].z); acc[3].w = fmaf(a0.w, b.w, acc[3].w);
          acc[4].x = fmaf(a1.x, b.x, acc[4].x); acc[4].y = fmaf(a1.x, b.y, acc[4].y);
          acc[4].z = fmaf(a1.x, b.z, acc[4].z); acc[4].w = fmaf(a1.x, b.w, acc[4].w);
          acc[5].x = fmaf(a1.y, b.x, acc[5].x); acc[5].y = fmaf(a1.y, b.y, acc[5].y);
          acc[5].z = fmaf(a1.y, b.z, acc[5].z); acc[5].w = fmaf(a1.y, b.w, acc[5].w);
          acc[6].x = fmaf(a1.z, b.x, acc[6].x); acc[6].y = fmaf(a1.z, b.y, acc[6].y);
          acc[6].z = fmaf(a1.z, b.z, acc[6].z); acc[6].w = fmaf(a1.z, b.w, acc[6].w);
          acc[7].x = fmaf(a1.w, b.x, acc[7].x); acc[7].y = fmaf(a1.w, b.y, acc[7].y);
          acc[7].z = fmaf(a1.w, b.z, acc[7].z); acc[7].w = fmaf(a1.w, b.w, acc[7].w);
        }
      }
      __syncthreads();  // ALL reads of AR/AT complete before overwrite
      if (active) {
#pragma unroll
        for (int j = 0; j < 8; ++j) AR4[(r0 + j) * 16 + c0q] = acc[j];
#pragma unroll
        for (int cj = 0; cj < 4; ++cj) {
          float4 lo = {CGET(acc[0], cj), CGET(acc[1], cj), CGET(acc[2], cj),
                       CGET(acc[3], cj)};
          float4 hi = {CGET(acc[4], cj), CGET(acc[5], cj), CGET(acc[6], cj),
                       CGET(acc[7], cj)};
          AT4[(4 * c0q + cj) * 16 + (r0 >> 2)] = lo;
          AT4[(4 * c0q + cj) * 16 + (r0 >> 2) + 1] = hi;
          if (s == 5) {
            *(float4*)&ws[P5T_OFF + (4 * c0q + cj) * 64 + r0] = lo;
            *(float4*)&ws[P5T_OFF + (4 * c0q + cj) * 64 + r0 + 4] = hi;
          }
        }
        if (s == 5 || s == 8 || s == 15) {
          const int off = (s == 5) ? P5R_OFF : (s == 8) ? P8R_OFF : P15_OFF;
#pragma unroll
          for (int j = 0; j < 8; ++j)
            *(float4*)&ws[off + (r0 + j) * 64 + 4 * c0q] = acc[j];
        }
      }
      __syncthreads();
    }
  }

  // ---- P4a: seeds. wave0: x_g=(Ab^32)^g Bb; wave1: r_g=(AbT^32)^g (AbT c)
  if (w == 0) {
    float4 m[16];
    load_rows(m, ws + P5R_OFF, lane);
    float x = ws[BB_OFF + lane];
    xs[0 * 68 + lane] = x;
#pragma unroll 1
    for (int g = 1; g < 8; ++g) {
      x = matvec64(m, x);
      xs[g * 68 + lane] = x;
    }
  } else if (w == 1) {
    float4 m[16];
    load_rows(m, ws + ABT_OFF, lane);
    float r = matvec64(m, Cv[lane]);  // Rtt[0] = Ab^T c
    load_rows(m, ws + P5T_OFF, lane);
    rs[0 * 68 + lane] = r;
#pragma unroll 1
    for (int g = 1; g < 8; ++g) {
      r = matvec64(m, r);
      rs[g * 68 + lane] = r;
    }
  }
  __syncthreads();

  // ---- P4b: X chains, 8 waves x 32 steps: Xcol[32w+j] = Ab^(32w+j) Bb
  {
    float4 m[16];
    load_rows(m, ws + ABR_OFF, lane);
    float x = xs[w * 68 + lane];
#pragma unroll 1
    for (int j = 0; j < 32; ++j) {
      ws[XCOL_OFF + (32 * w + j) * 64 + lane] = x;
      if (j < 31) x = matvec64(m, x);
    }
  }
  // ---- P4c: R chains: Rtt[32w+j] = (AbT)^(32w+j+1) c
  {
    float4 m[16];
    load_rows(m, ws + ABT_OFF, lane);
    float r = rs[w * 68 + lane];
#pragma unroll 1
    for (int j = 0; j < 32; ++j) {
      ws[RTT_OFF + (32 * w + j) * 64 + lane] = r;
      if (j < 31) r = matvec64(m, r);
    }
  }
  __syncthreads();

  // ---- P4d: transpose Rtt[i][n] -> Rt[n][MC]
  {
    float* tr = sm + 8192;  // [64][65]
    for (int blk = 0; blk < 4; ++blk) {
      for (int idx = t; idx < 4096; idx += 512) {
        int il = idx >> 6, nn = idx & 63;
        tr[nn * 65 + il] = ws[RTT_OFF + (blk * 64 + il) * 64 + nn];
      }
      __syncthreads();
      for (int idx = t; idx < 4096; idx += 512) {
        int nn = idx >> 6, il = idx & 63;
        ws[RT_OFF + nn * MC + blk * 64 + il] = tr[nn * 65 + il];
      }
      __syncthreads();
    }
  }

  // ---- P5: Kloc[i] = Cb . Xcol[i]  (shuffle reduce)
  {
    const float cv = Cv[lane];
    for (int i = w; i < MC; i += 8) {
      float p = cv * ws[XCOL_OFF + i * 64 + lane];
#pragma unroll
      for (int m = 32; m >= 1; m >>= 1) p += __shfl_xor(p, m, 64);
      if (lane == 0) ws[KL_OFF + i] = p;
    }
  }
}

// ---------------------------------------------------------------------
// K2: F[c][n] = sum_j Xcol[MC-1-j][n] * u[c*MC+j]. 16 chunks per block.
// ---------------------------------------------------------------------
__global__ __launch_bounds__(256) void k_f(const float* __restrict__ u,
                                           float* __restrict__ ws) {
  __shared__ __align__(16) float us[16 * MC];
  const int t = threadIdx.x;
  const int c0 = blockIdx.x * 16;
  for (int idx = t; idx < 16 * MC; idx += 256)
    us[idx] = u[(size_t)c0 * MC + idx];
  __syncthreads();
  const int n = t & 63, g = t >> 6;  // wave g owns chunks c0+4g..c0+4g+3
  const float* xc = ws + XCOL_OFF;
  const float* ug = us + g * 4 * MC;
  float a0 = 0.f, a1 = 0.f, a2 = 0.f, a3 = 0.f;
  for (int j = 0; j < MC; j += 4) {
    float x0 = xc[(MC - 1 - j) * 64 + n];
    float x1 = xc[(MC - 2 - j) * 64 + n];
    float x2 = xc[(MC - 3 - j) * 64 + n];
    float x3 = xc[(MC - 4 - j) * 64 + n];
    {
      const float4 uv = *(const float4*)&ug[0 * MC + j];
      a0 += x0 * uv.x + x1 * uv.y + x2 * uv.z + x3 * uv.w;
    }
    {
      const float4 uv = *(const float4*)&ug[1 * MC + j];
      a1 += x0 * uv.x + x1 * uv.y + x2 * uv.z + x3 * uv.w;
    }
    {
      const float4 uv = *(const float4*)&ug[2 * MC + j];
      a2 += x0 * uv.x + x1 * uv.y + x2 * uv.z + x3 * uv.w;
    }
    {
      const float4 uv = *(const float4*)&ug[3 * MC + j];
      a3 += x0 * uv.x + x1 * uv.y + x2 * uv.z + x3 * uv.w;
    }
  }
  float* Fb = ws + F_OFF + (c0 + g * 4) * 64;
  Fb[0 * 64 + n] = a0;
  Fb[1 * 64 + n] = a1;
  Fb[2 * 64 + n] = a2;
  Fb[3 * 64 + n] = a3;
}

// ---------------------------------------------------------------------
// Scan kernels: one wave scans (P rows in regs, readlane bcast), 8-deep
// global prefetch; an extra wave helps load the P matrix then exits.
// (128,1) launch bounds: p[64] needs ~110 VGPRs -> must not be capped
// at the 64-VGPR full-occupancy default (round-6 spill lesson).
// ---------------------------------------------------------------------
#define MATVEC_STEP(preg, xv, a0, a1, a2, a3)          \
  _Pragma("unroll") for (int k = 0; k < 64; k += 4) {  \
    a0 = fmaf(preg[k + 0], bcast(xv, k + 0), a0);      \
    a1 = fmaf(preg[k + 1], bcast(xv, k + 1), a1);      \
    a2 = fmaf(preg[k + 2], bcast(xv, k + 2), a2);      \
    a3 = fmaf(preg[k + 3], bcast(xv, k + 3), a3);      \
  }

__global__ __launch_bounds__(128, 1) void k_scan1(float* __restrict__ ws) {
  __shared__ float Pl[4160];
  const int t = threadIdx.x;
  for (int idx = t; idx < 4096; idx += 128)
    Pl[(idx >> 6) * 65 + (idx & 63)] = ws[P8R_OFF + idx];
  __syncthreads();
  if (t >= 64) return;
  const int n = t;
  float p[64];
#pragma unroll
  for (int k = 0; k < 64; ++k) p[k] = Pl[n * 65 + k];
  float x = 0.f;
  const float* Fp = ws + F_OFF + blockIdx.x * SEG * 64;
  float fc[8], fn[8];
#pragma unroll
  for (int i = 0; i < 8; ++i) fc[i] = Fp[i * 64 + n];
  for (int c0 = 0; c0 < SEG; c0 += 8) {
#pragma unroll
    for (int i = 0; i < 8; ++i) {
      int cn = c0 + 8 + i;
      if (cn > SEG - 1) cn = SEG - 1;
      fn[i] = Fp[cn * 64 + n];
    }
#pragma unroll
    for (int i = 0; i < 8; ++i) {
      float a0 = 0.f, a1 = 0.f, a2 = 0.f, a3 = 0.f;
      MATVEC_STEP(p, x, a0, a1, a2, a3)
      x = ((a0 + a1) + (a2 + a3)) + fc[i];
    }
#pragma unroll
    for (int i = 0; i < 8; ++i) fc[i] = fn[i];
  }
  ws[CARRY_OFF + blockIdx.x * 64 + n] = x;
}

__global__ __launch_bounds__(128, 1) void k_scantop(float* __restrict__ ws) {
  __shared__ float Ql[4160];
  const int t = threadIdx.x;
  for (int idx = t; idx < 4096; idx += 128)
    Ql[(idx >> 6) * 65 + (idx & 63)] = ws[P15_OFF + idx];
  __syncthreads();
  if (t >= 64) return;
  const int n = t;
  float q[64];
#pragma unroll
  for (int k = 0; k < 64; ++k) q[k] = Ql[n * 65 + k];
  float x = 0.f;
  float fc[8], fn[8];
#pragma unroll
  for (int i = 0; i < 8; ++i) fc[i] = ws[CARRY_OFF + i * 64 + n];
  for (int s0 = 0; s0 < NSEG; s0 += 8) {
#pragma unroll
    for (int i = 0; i < 8; ++i) {
      int sn = s0 + 8 + i;
      if (sn > NSEG - 1) sn = NSEG - 1;
      fn[i] = ws[CARRY_OFF + sn * 64 + n];
    }
#pragma unroll
    for (int i = 0; i < 8; ++i) {
      ws[SEGINIT_OFF + (s0 + i) * 64 + n] = x;  // exclusive prefix state
      float a0 = 0.f, a1 = 0.f, a2 = 0.f, a3 = 0.f;
      MATVEC_STEP(q, x, a0, a1, a2, a3)
      x = ((a0 + a1) + (a2 + a3)) + fc[i];
    }
#pragma unroll
    for (int i = 0; i < 8; ++i) fc[i] = fn[i];
  }
}

__global__ __launch_bounds__(128, 1) void k_scan2(float* __restrict__ ws) {
  __shared__ float Pl[4160];
  const int t = threadIdx.x;
  for (int idx = t; idx < 4096; idx += 128)
    Pl[(idx >> 6) * 65 + (idx & 63)] = ws[P8R_OFF + idx];
  __syncthreads();
  if (t >= 64) return;
  const int n = t;
  float p[64];
#pragma unroll
  for (int k = 0; k < 64; ++k) p[k] = Pl[n * 65 + k];
  float x = ws[SEGINIT_OFF + blockIdx.x * 64 + n];
  float* Fp = ws + F_OFF + blockIdx.x * SEG * 64;
  float fc[8], fn[8];
#pragma unroll
  for (int i = 0; i < 8; ++i) fc[i] = Fp[i * 64 + n];
  for (int c0 = 0; c0 < SEG; c0 += 8) {
#pragma unroll
    for (int i = 0; i < 8; ++i) {
      int cn = c0 + 8 + i;
      if (cn > SEG - 1) cn = SEG - 1;
      fn[i] = Fp[cn * 64 + n];
    }
#pragma unroll
    for (int i = 0; i < 8; ++i) {
      float fv = fc[i];
      Fp[(c0 + i) * 64 + n] = x;  // F becomes Xinit[c] (state BEFORE chunk)
      float a0 = 0.f, a1 = 0.f, a2 = 0.f, a3 = 0.f;
      MATVEC_STEP(p, x, a0, a1, a2, a3)
      x = ((a0 + a1) + (a2 + a3)) + fv;
    }
#pragma unroll
    for (int i = 0; i < 8; ++i) fc[i] = fn[i];
  }
}

// ---------------------------------------------------------------------
// K6: y[c*MC+i] = Rt[:,i].Xinit[c] + tri-conv(Kloc,u) + D*u. 8 chunks/blk.
// ---------------------------------------------------------------------
__global__ __launch_bounds__(256) void k_final(const float* __restrict__ u,
                                               const float* __restrict__ Dv,
                                               const float* __restrict__ ws,
                                               float* __restrict__ out) {
  __shared__ __align__(16) float us[8 * MC];
  __shared__ __align__(16) float kl[MC];
  __shared__ __align__(16) float xin[8 * 64];
  const int t = threadIdx.x;
  const int c0 = blockIdx.x * 8;
  for (int idx = t; idx < 8 * MC; idx += 256)
    us[idx] = u[(size_t)c0 * MC + idx];
  kl[t] = ws[KL_OFF + t];
  for (int idx = t; idx < 8 * 64; idx += 256)
    xin[idx] = ws[F_OFF + c0 * 64 + idx];
  __syncthreads();

  float acc[8];
#pragma unroll
  for (int cc = 0; cc < 8; ++cc) acc[cc] = 0.f;

  const float* rt = ws + RT_OFF;
#pragma unroll 4
  for (int nn = 0; nn < 64; nn += 4) {
    float r0 = rt[(nn + 0) * MC + t];
    float r1 = rt[(nn + 1) * MC + t];
    float r2 = rt[(nn + 2) * MC + t];
    float r3 = rt[(nn + 3) * MC + t];
#pragma unroll
    for (int cc = 0; cc < 8; ++cc) {
      const float4 xv = *(const float4*)&xin[cc * 64 + nn];
      acc[cc] += r0 * xv.x + r1 * xv.y + r2 * xv.z + r3 * xv.w;
    }
  }

  const int i = t;
  int j = 0;
  for (; j + 3 <= i; j += 4) {
    float k0 = kl[i - j], k1 = kl[i - j - 1], k2 = kl[i - j - 2],
          k3 = kl[i - j - 3];
#pragma unroll
    for (int cc = 0; cc < 8; ++cc) {
      const float4 uv = *(const float4*)&us[cc * MC + j];
      acc[cc] += k0 * uv.x + k1 * uv.y + k2 * uv.z + k3 * uv.w;
    }
  }
  for (; j <= i; ++j) {
    float kv = kl[i - j];
#pragma unroll
    for (int cc = 0; cc < 8; ++cc) acc[cc] += kv * us[cc * MC + j];
  }

  const float D0 = Dv[0];
#pragma unroll
  for (int cc = 0; cc < 8; ++cc)
    out[(size_t)(c0 + cc) * MC + i] = acc[cc] + D0 * us[cc * MC + i];
}

// ---------------------------------------------------------------------
extern "C" void kernel_launch(void* const* d_in, const int* in_sizes, int n_in,
                              void* d_out, int out_size, void* d_ws,
                              size_t ws_size, hipStream_t stream) {
  (void)in_sizes; (void)n_in; (void)out_size; (void)ws_size;
  const float* u = (const float*)d_in[0];
  const float* A = (const float*)d_in[1];
  const float* B = (const float*)d_in[2];
  const float* C = (const float*)d_in[3];
  const float* D = (const float*)d_in[4];
  const float* ls = (const float*)d_in[5];
  float* ws = (float*)d_ws;  // needs WS_FLOATS*4 ~ 4.34 MB
  float* out = (float*)d_out;

  hipLaunchKernelGGL(k_setup, dim3(1), dim3(512), 0, stream, A, B, C, ls, ws);
  hipLaunchKernelGGL(k_f, dim3(NCHUNK / 16), dim3(256), 0, stream, u, ws);
  hipLaunchKernelGGL(k_scan1, dim3(NSEG), dim3(128), 0, stream, ws);
  hipLaunchKernelGGL(k_scantop, dim3(1), dim3(128), 0, stream, ws);
  hipLaunchKernelGGL(k_scan2, dim3(NSEG), dim3(128), 0, stream, ws);
  hipLaunchKernelGGL(k_final, dim3(NCHUNK / 8), dim3(256), 0, stream, u, D, ws,
                     out);
}